// Round 6
// baseline (214.137 us; speedup 1.0000x reference)
//
#include <hip/hip_runtime.h>
#include <cmath>
#include <cstdint>

// Instant-NGP hash-grid encoder, level-phased for L2 residency.
// R6 = R5 (best: 213.4 us) + L1-bypass probe: nontemporal (nt) loads on table
// gathers for levels whose table > 128KB (L1 hit rate ~0-8% there; the nt hint
// skips L1 allocate/fill overhead if Model B holds; neutral if MSHR-bound).
//
// Kernel A (gather): grid (B/256, 16). blockIdx.y = level -> concurrently
//   resident blocks share 1-2 levels -> each XCD's 4MB L2 holds the live
//   level's table (fast tables are exactly 4MB). Writes ws[l*B+b] coalesced.
// Kernel B (transpose): ws[l][b] -> out[b*16+l] via LDS 16x64 tiles.

#define NLEVELS 16
#define BPOINTS 524288

struct LevelMeta {
    float    scale[NLEVELS];
    uint32_t size[NLEVELS];     // entries
    uint32_t offset[NLEVELS];   // float2 units
    uint32_t mul_y[NLEVELS];    // dense: r    ; fast: 2654435761
    uint32_t mul_z[NLEVELS];    // dense: r*r  ; fast: 805459861
    uint32_t fast[NLEVELS];
    uint32_t bypass[NLEVELS];   // 1 if table > 128KB -> nt (L1-bypass) gathers
};

__device__ __forceinline__ float2 ld_tbl(const float2* p, bool nt_hint)
{
    if (nt_hint) {
        // 8B nontemporal load: global_load_dwordx2 ... nt (no L1 allocate)
        unsigned long long raw =
            __builtin_nontemporal_load(reinterpret_cast<const unsigned long long*>(p));
        union { unsigned long long u; float2 f; } cv;
        cv.u = raw;
        return cv.f;
    }
    return *p;
}

__device__ __forceinline__ void encode_one(
    const float* __restrict__ pos, const float2* __restrict__ tbl,
    int b, int l, const LevelMeta& meta, float& o0, float& o1)
{
    const float x = pos[b * 3 + 0];
    const float y = pos[b * 3 + 1];
    const float z = pos[b * 3 + 2];

    const float s = meta.scale[l];
    const float px = __fadd_rn(__fmul_rn(x, s), 0.5f);
    const float py = __fadd_rn(__fmul_rn(y, s), 0.5f);
    const float pz = __fadd_rn(__fmul_rn(z, s), 0.5f);

    const float gx = floorf(px), gy = floorf(py), gz = floorf(pz);
    const float fx = px - gx,    fy = py - gy,    fz = pz - gz;

    const uint32_t ix = (uint32_t)gx, iy = (uint32_t)gy, iz = (uint32_t)gz;

    const uint32_t size  = meta.size[l];
    const uint32_t off   = meta.offset[l];
    const uint32_t my    = meta.mul_y[l];
    const uint32_t mz    = meta.mul_z[l];
    const bool     fastl = meta.fast[l]   != 0;  // block-uniform (l = blockIdx.y)
    const bool     ntl   = meta.bypass[l] != 0;  // block-uniform
    const uint32_t mask  = size - 1u;            // fast levels: size == 2^19

    const uint32_t hx0 = ix,      hx1 = ix + 1u;
    const uint32_t hy0 = iy * my, hy1 = hy0 + my;
    const uint32_t hz0 = iz * mz, hz1 = hz0 + mz;

    const float wx0 = 1.0f - fx, wx1 = fx;
    const float wy0 = 1.0f - fy, wy1 = fy;
    const float wz0 = 1.0f - fz, wz1 = fz;

    uint32_t idx[8];
#pragma unroll
    for (int c = 0; c < 8; ++c) {
        const uint32_t hxv = (c & 1) ? hx1 : hx0;
        const uint32_t hyv = (c & 2) ? hy1 : hy0;
        const uint32_t hzv = (c & 4) ? hz1 : hz0;
        uint32_t h;
        if (fastl) {
            h = (hxv ^ hyv ^ hzv) & mask;
        } else {
            h = hxv + hyv + hzv;                 // < 2*size -> one conditional subtract
            h = (h >= size) ? (h - size) : h;
        }
        idx[c] = off + h;
    }

    // all 8 gathers in flight before any use
    float2 f[8];
#pragma unroll
    for (int c = 0; c < 8; ++c) f[c] = ld_tbl(&tbl[idx[c]], ntl);

    o0 = 0.0f; o1 = 0.0f;
#pragma unroll
    for (int c = 0; c < 8; ++c) {
        const float wxv = (c & 1) ? wx1 : wx0;
        const float wyv = (c & 2) ? wy1 : wy0;
        const float wzv = (c & 4) ? wz1 : wz0;
        const float w = __fmul_rn(__fmul_rn(wxv, wyv), wzv);  // jnp.prod order
        o0 = __fmaf_rn(w, f[c].x, o0);
        o1 = __fmaf_rn(w, f[c].y, o1);
    }
}

// ---- Kernel A: phased gather, level-major ws output ----
__global__ __launch_bounds__(256) void hashenc_gather(
    const float*  __restrict__ pos,
    const float2* __restrict__ tbl,
    float2*       __restrict__ ws,
    LevelMeta meta)
{
    const int l = blockIdx.y;                       // wave-uniform level -> SGPR meta
    const int b = blockIdx.x * 256 + threadIdx.x;
    float o0, o1;
    encode_one(pos, tbl, b, l, meta, o0, o1);
    ws[(size_t)l * BPOINTS + b] = make_float2(o0, o1);   // coalesced
}

// ---- Kernel B: transpose ws[l][b] -> out[b*16+l], LDS 16x64 tiles ----
__global__ __launch_bounds__(256) void hashenc_transpose(
    const float2* __restrict__ ws,
    float2*       __restrict__ out)
{
    __shared__ float2 tile[NLEVELS][65];            // +1 pad breaks bank conflicts
    const int b0  = blockIdx.x * 64;
    const int tid = threadIdx.x;

#pragma unroll
    for (int k = 0; k < 4; ++k) {
        const int idx = k * 256 + tid;              // [0,1024)
        const int l = idx >> 6, j = idx & 63;
        tile[l][j] = ws[(size_t)l * BPOINTS + b0 + j];   // 512B/row coalesced
    }
    __syncthreads();
#pragma unroll
    for (int k = 0; k < 4; ++k) {
        const int idx = k * 256 + tid;              // flat out index within tile
        const int j = idx >> 4, l = idx & 15;
        union { float2 f2; unsigned long long u64; } u;
        u.f2 = tile[l][j];
        __builtin_nontemporal_store(u.u64,
            (unsigned long long*)&out[(size_t)b0 * NLEVELS + idx]);  // 2KB contiguous
    }
}

// ---- Fallback (point-major, direct write) if workspace too small ----
__global__ __launch_bounds__(256) void hashenc_direct(
    const float*  __restrict__ pos,
    const float2* __restrict__ tbl,
    float2*       __restrict__ out,
    LevelMeta meta)
{
    const int t = blockIdx.x * 256 + threadIdx.x;
    const int b = t >> 4;
    const int l = t & 15;
    float o0, o1;
    encode_one(pos, tbl, b, l, meta, o0, o1);
    union { float2 f2; unsigned long long u64; } u;
    u.f2 = make_float2(o0, o1);
    __builtin_nontemporal_store(u.u64, (unsigned long long*)&out[t]);
}

static void fill_meta(LevelMeta& m)
{
    const double PLS = 1.3195079565048218;
    const uint32_t P1 = 2654435761u, P2 = 805459861u;
    const long long MAXP = 1ll << 19;
    long long off = 0;
    for (int i = 0; i < NLEVELS; ++i) {
        const double scale_d = 16.0 * pow(PLS, (double)i) - 1.0;
        const long long r = (long long)ceil(scale_d) + 1;
        const long long full = r * r * r;
        const long long aligned = ((full + 7) / 8) * 8;
        const long long p = aligned < MAXP ? aligned : MAXP;
        const bool fast = full > p;
        m.scale[i]  = (float)scale_d;
        m.size[i]   = (uint32_t)p;
        m.offset[i] = (uint32_t)off;
        m.mul_y[i]  = fast ? P1 : (uint32_t)r;
        m.mul_z[i]  = fast ? P2 : (uint32_t)(r * r);
        m.fast[i]   = fast ? 1u : 0u;
        // table bytes = p * 8; bypass L1 when it can't usefully cache (>128KB)
        m.bypass[i] = (p * 8 > 131072) ? 1u : 0u;
        off += p;
    }
}

extern "C" void kernel_launch(void* const* d_in, const int* in_sizes, int n_in,
                              void* d_out, int out_size, void* d_ws, size_t ws_size,
                              hipStream_t stream)
{
    const float*  positions = (const float*)d_in[0];
    const float2* table     = (const float2*)d_in[1];
    float2*       out       = (float2*)d_out;

    LevelMeta m;
    fill_meta(m);

    const size_t ws_need = (size_t)BPOINTS * NLEVELS * sizeof(float2);  // 64 MB
    if (ws_size >= ws_need) {
        dim3 grid(BPOINTS / 256, NLEVELS);
        hashenc_gather<<<grid, 256, 0, stream>>>(positions, table, (float2*)d_ws, m);
        hashenc_transpose<<<BPOINTS / 64, 256, 0, stream>>>((const float2*)d_ws, out);
    } else {
        hashenc_direct<<<(BPOINTS * NLEVELS) / 256, 256, 0, stream>>>(positions, table, out, m);
    }
}